// Round 2
// baseline (770.783 us; speedup 1.0000x reference)
//
#include <hip/hip_runtime.h>

#define EPSF 1e-8f

// ws layout (as unsigned u[]):
//  u[0..3]   : maxabs bits of noise LL/LH/HL/HH (non-negative float bits) — memset 0
//  u[4..7]   : folded coefficients cLL,cLH,cHL,cHH (float)                — written by k_prep
//  u[8..23]  : per-batch MAX as ordered-uint key                          — memset 0x00
//  u[24..39] : per-batch MIN as ordered-uint key                          — memset 0xFF

__device__ __forceinline__ unsigned f2key(float f) {
    unsigned b = __float_as_uint(f);
    return (b & 0x80000000u) ? ~b : (b | 0x80000000u);
}
__device__ __forceinline__ float key2f(unsigned k) {
    unsigned b = (k & 0x80000000u) ? (k & 0x7fffffffu) : ~k;
    return __uint_as_float(b);
}

// ---------------- K1: max |noise| per tensor ----------------
__global__ void k_maxabs(const float* __restrict__ n0, const float* __restrict__ n1,
                         const float* __restrict__ n2, const float* __restrict__ n3,
                         unsigned* __restrict__ u, int n4) {
    const float* p = (blockIdx.y == 0) ? n0 : (blockIdx.y == 1) ? n1 : (blockIdx.y == 2) ? n2 : n3;
    const float4* p4 = (const float4*)p;
    unsigned m = 0u;
    int stride = gridDim.x * blockDim.x;
    for (int i = blockIdx.x * blockDim.x + threadIdx.x; i < n4; i += stride) {
        float4 v = p4[i];
        unsigned a = __float_as_uint(v.x) & 0x7fffffffu;
        unsigned b = __float_as_uint(v.y) & 0x7fffffffu;
        unsigned c = __float_as_uint(v.z) & 0x7fffffffu;
        unsigned d = __float_as_uint(v.w) & 0x7fffffffu;
        m = max(m, max(max(a, b), max(c, d)));
    }
    for (int off = 32; off > 0; off >>= 1) m = max(m, __shfl_down(m, off, 64));
    __shared__ unsigned sm[4];
    int lane = threadIdx.x & 63, wv = threadIdx.x >> 6;
    if (lane == 0) sm[wv] = m;
    __syncthreads();
    if (threadIdx.x == 0) {
        unsigned r = max(max(sm[0], sm[1]), max(sm[2], sm[3]));
        atomicMax(&u[blockIdx.y], r);
    }
}

// ---------------- K2: fold coefficients (1 thread) ----------------
__global__ void k_prep(unsigned* __restrict__ u) {
    if (threadIdx.x == 0 && blockIdx.x == 0) {
        float* f = (float*)u;
        // c = 0.5 * alpha / (maxabs + eps); ALPHA_LOW=0.2, ALPHA_HIGH=1.0
        f[4] = 0.1f / (__uint_as_float(u[0]) + EPSF);
        f[5] = 0.5f / (__uint_as_float(u[1]) + EPSF);
        f[6] = 0.5f / (__uint_as_float(u[2]) + EPSF);
        f[7] = 0.5f / (__uint_as_float(u[3]) + EPSF);
    }
}

// ---------------- K3: compute enc, store to out, per-batch min/max ----------------
// Thread handles 2 rows x 4 cols. idx -> w4 (0..255), h2 (0..511), bc (0..47).
// Block of 256 spans exactly the w4 axis -> bc uniform within block.
__global__ void k_enc_minmax(const float* __restrict__ img,
                             const float* __restrict__ nLL, const float* __restrict__ nLH,
                             const float* __restrict__ nHL, const float* __restrict__ nHH,
                             unsigned* __restrict__ u, float* __restrict__ out) {
    int idx = blockIdx.x * blockDim.x + threadIdx.x;
    int w4 = idx & 255;
    int h2 = (idx >> 8) & 511;
    int bc = idx >> 17;
    const float* fu = (const float*)u;
    float cLL = fu[4], cLH = fu[5], cHL = fu[6], cHH = fu[7];
    int noff = (bc * 512 + h2) * 512 + 2 * w4;
    float2 vLL = *(const float2*)(nLL + noff);
    float2 vLH = *(const float2*)(nLH + noff);
    float2 vHL = *(const float2*)(nHL + noff);
    float2 vHH = *(const float2*)(nHH + noff);
    int ioff = (bc * 1024 + 2 * h2) * 1024 + 4 * w4;
    float4 r0 = *(const float4*)(img + ioff);
    float4 r1 = *(const float4*)(img + ioff + 1024);
    float tLL0 = cLL * vLL.x, tLL1 = cLL * vLL.y;
    float tLH0 = cLH * vLH.x, tLH1 = cLH * vLH.y;
    float tHL0 = cHL * vHL.x, tHL1 = cHL * vHL.y;
    float tHH0 = cHH * vHH.x, tHH1 = cHH * vHH.y;
    float4 o0, o1;
    o0.x = r0.x + (tLL0 + tLH0 + tHL0 + tHH0);
    o0.y = r0.y + (tLL0 + tLH0 - tHL0 - tHH0);
    o0.z = r0.z + (tLL1 + tLH1 + tHL1 + tHH1);
    o0.w = r0.w + (tLL1 + tLH1 - tHL1 - tHH1);
    o1.x = r1.x + (tLL0 - tLH0 + tHL0 - tHH0);
    o1.y = r1.y + (tLL0 - tLH0 - tHL0 + tHH0);
    o1.z = r1.z + (tLL1 - tLH1 + tHL1 - tHH1);
    o1.w = r1.w + (tLL1 - tLH1 - tHL1 + tHH1);
    *(float4*)(out + ioff) = o0;
    *(float4*)(out + ioff + 1024) = o1;

    float mn = fminf(fminf(fminf(o0.x, o0.y), fminf(o0.z, o0.w)),
                     fminf(fminf(o1.x, o1.y), fminf(o1.z, o1.w)));
    float mx = fmaxf(fmaxf(fmaxf(o0.x, o0.y), fmaxf(o0.z, o0.w)),
                     fmaxf(fmaxf(o1.x, o1.y), fmaxf(o1.z, o1.w)));
    unsigned kmn = f2key(mn), kmx = f2key(mx);
    for (int off = 32; off > 0; off >>= 1) {
        kmn = min(kmn, __shfl_down(kmn, off, 64));
        kmx = max(kmx, __shfl_down(kmx, off, 64));
    }
    __shared__ unsigned smn[4], smx[4];
    int lane = threadIdx.x & 63, wv = threadIdx.x >> 6;
    if (lane == 0) { smn[wv] = kmn; smx[wv] = kmx; }
    __syncthreads();
    if (threadIdx.x == 0) {
        unsigned rmn = min(min(smn[0], smn[1]), min(smn[2], smn[3]));
        unsigned rmx = max(max(smx[0], smx[1]), max(smx[2], smx[3]));
        int b = (unsigned)bc / 3u;
        atomicMin(&u[24 + b], rmn);
        atomicMax(&u[8 + b], rmx);
    }
}

// ---------------- K4: in-place normalize (reads enc from L3) ----------------
__global__ void k_norm(float* __restrict__ out, const unsigned* __restrict__ u, int n4) {
    const int F4_PER_BATCH = 3 * 1024 * 1024 / 4;  // 786432 float4 per batch
    int stride = gridDim.x * blockDim.x;
    float4* o4 = (float4*)out;
    for (int i = blockIdx.x * blockDim.x + threadIdx.x; i < n4; i += stride) {
        int b = (unsigned)i / (unsigned)F4_PER_BATCH;
        float mnf = key2f(u[24 + b]);
        float mxf = key2f(u[8 + b]);
        float inv = 1.0f / fmaxf(mxf - mnf, EPSF);
        float4 v = o4[i];
        v.x = (v.x - mnf) * inv;
        v.y = (v.y - mnf) * inv;
        v.z = (v.z - mnf) * inv;
        v.w = (v.w - mnf) * inv;
        o4[i] = v;
    }
}

extern "C" void kernel_launch(void* const* d_in, const int* in_sizes, int n_in,
                              void* d_out, int out_size, void* d_ws, size_t ws_size,
                              hipStream_t stream) {
    const float* img = (const float*)d_in[0];
    const float* nLL = (const float*)d_in[1];
    const float* nLH = (const float*)d_in[2];
    const float* nHL = (const float*)d_in[3];
    const float* nHH = (const float*)d_in[4];
    unsigned* u = (unsigned*)d_ws;
    float* out = (float*)d_out;

    // init reduction slots (ws is poisoned 0xAA before every call)
    hipMemsetAsync(d_ws, 0x00, 96, stream);                 // u[0..23]
    hipMemsetAsync((char*)d_ws + 96, 0xFF, 64, stream);     // u[24..39]

    const int n4_noise = (16 * 3 * 512 * 512) / 4;  // 3,145,728 float4 per noise tensor
    dim3 g1(512, 4);
    k_maxabs<<<g1, 256, 0, stream>>>(nLL, nLH, nHL, nHH, u, n4_noise);
    k_prep<<<1, 64, 0, stream>>>(u);

    const int blocks = (16 * 3 * 512 * 256) / 256;  // 24576 blocks of 256
    k_enc_minmax<<<blocks, 256, 0, stream>>>(img, nLL, nLH, nHL, nHH, u, out);

    const int n4_out = (16 * 3 * 1024 * 1024) / 4;  // 12,582,912 float4
    k_norm<<<2048, 256, 0, stream>>>(out, u, n4_out);
}

// Round 5
// 557.935 us; speedup vs baseline: 1.3815x; 1.3815x over previous
//
#include <hip/hip_runtime.h>

#define EPSF 1e-8f

// ws layout (as unsigned u[]):
//  u[0..3]   : maxabs bits of noise LL/LH/HL/HH (non-negative float bits) — memset 0x00
//  u[8..23]  : per-batch MAX as ordered-uint key                          — memset 0x00
//  u[24..39] : per-batch MIN as ordered-uint key                          — memset 0xFF

typedef __attribute__((ext_vector_type(4))) float f32x4;

__device__ __forceinline__ unsigned f2key(float f) {
    unsigned b = __float_as_uint(f);
    return (b & 0x80000000u) ? ~b : (b | 0x80000000u);
}
__device__ __forceinline__ float key2f(unsigned k) {
    unsigned b = (k & 0x80000000u) ? (k & 0x7fffffffu) : ~k;
    return __uint_as_float(b);
}

// ---------------- K1: max |noise| per tensor ----------------
// grid (512, 4) x 256. S = 131072 threads per tensor; n4 = 3,145,728 = 24*S.
// Unroll x4: each wave keeps 4 coalesced 1KB loads in flight.
__global__ void k_maxabs(const float* __restrict__ n0, const float* __restrict__ n1,
                         const float* __restrict__ n2, const float* __restrict__ n3,
                         unsigned* __restrict__ u, int n4) {
    const float* p = (blockIdx.y == 0) ? n0 : (blockIdx.y == 1) ? n1 : (blockIdx.y == 2) ? n2 : n3;
    const float4* p4 = (const float4*)p;
    int tid = blockIdx.x * blockDim.x + threadIdx.x;
    int S = gridDim.x * blockDim.x;
    unsigned m = 0u;
    for (int i = tid; i + 3 * S < n4; i += 4 * S) {
        float4 a = p4[i], b = p4[i + S], c = p4[i + 2 * S], d = p4[i + 3 * S];
        unsigned m0 = max(__float_as_uint(a.x) & 0x7fffffffu, __float_as_uint(a.y) & 0x7fffffffu);
        unsigned m1 = max(__float_as_uint(a.z) & 0x7fffffffu, __float_as_uint(a.w) & 0x7fffffffu);
        unsigned m2 = max(__float_as_uint(b.x) & 0x7fffffffu, __float_as_uint(b.y) & 0x7fffffffu);
        unsigned m3 = max(__float_as_uint(b.z) & 0x7fffffffu, __float_as_uint(b.w) & 0x7fffffffu);
        unsigned m4 = max(__float_as_uint(c.x) & 0x7fffffffu, __float_as_uint(c.y) & 0x7fffffffu);
        unsigned m5 = max(__float_as_uint(c.z) & 0x7fffffffu, __float_as_uint(c.w) & 0x7fffffffu);
        unsigned m6 = max(__float_as_uint(d.x) & 0x7fffffffu, __float_as_uint(d.y) & 0x7fffffffu);
        unsigned m7 = max(__float_as_uint(d.z) & 0x7fffffffu, __float_as_uint(d.w) & 0x7fffffffu);
        m = max(m, max(max(max(m0, m1), max(m2, m3)), max(max(m4, m5), max(m6, m7))));
    }
    for (int off = 32; off > 0; off >>= 1) m = max(m, __shfl_down(m, off, 64));
    __shared__ unsigned sm[4];
    int lane = threadIdx.x & 63, wv = threadIdx.x >> 6;
    if (lane == 0) sm[wv] = m;
    __syncthreads();
    if (threadIdx.x == 0) {
        unsigned r = max(max(sm[0], sm[1]), max(sm[2], sm[3]));
        atomicMax(&u[blockIdx.y], r);
    }
}

// ---------------- K3: compute enc, store to out, per-batch min/max ----------------
// grid (256, 16) x 256; blockIdx.y = batch. Per batch: items = 3*512*256 = 393216,
// threads = 65536, 6 items/thread, unroll x2 -> 3 iterations with 12 loads in flight.
// Coefficients (prep) computed inline from u[0..3] — k_prep kernel eliminated.
__global__ void k_enc_minmax(const float* __restrict__ img,
                             const float* __restrict__ nLL, const float* __restrict__ nLH,
                             const float* __restrict__ nHL, const float* __restrict__ nHH,
                             unsigned* __restrict__ u, float* __restrict__ out) {
    const int b = blockIdx.y;
    const int S = gridDim.x * blockDim.x;       // 65536
    const int tid = blockIdx.x * blockDim.x + threadIdx.x;
    const int ITEMS = 3 * 512 * 256;            // per batch

    // fold normalization + alpha + idwt 0.5 into one coeff per subband
    float cLL = 0.1f / (__uint_as_float(u[0]) + EPSF);
    float cLH = 0.5f / (__uint_as_float(u[1]) + EPSF);
    float cHL = 0.5f / (__uint_as_float(u[2]) + EPSF);
    float cHH = 0.5f / (__uint_as_float(u[3]) + EPSF);

    float mn = 3.4e38f, mx = -3.4e38f;

    for (int j0 = tid; j0 + S < ITEMS; j0 += 2 * S) {
        int noff[2], ioff[2];
#pragma unroll
        for (int t = 0; t < 2; ++t) {
            int j = j0 + t * S;
            int w4 = j & 255, h2 = (j >> 8) & 511, c = j >> 17;
            int bc = b * 3 + c;
            noff[t] = (bc * 512 + h2) * 512 + 2 * w4;
            ioff[t] = (bc * 1024 + 2 * h2) * 1024 + 4 * w4;
        }
        float2 vLL[2], vLH[2], vHL[2], vHH[2];
        float4 r0[2], r1[2];
#pragma unroll
        for (int t = 0; t < 2; ++t) {
            vLL[t] = *(const float2*)(nLL + noff[t]);
            vLH[t] = *(const float2*)(nLH + noff[t]);
            vHL[t] = *(const float2*)(nHL + noff[t]);
            vHH[t] = *(const float2*)(nHH + noff[t]);
            r0[t] = *(const float4*)(img + ioff[t]);
            r1[t] = *(const float4*)(img + ioff[t] + 1024);
        }
#pragma unroll
        for (int t = 0; t < 2; ++t) {
            float tLL0 = cLL * vLL[t].x, tLL1 = cLL * vLL[t].y;
            float tLH0 = cLH * vLH[t].x, tLH1 = cLH * vLH[t].y;
            float tHL0 = cHL * vHL[t].x, tHL1 = cHL * vHL[t].y;
            float tHH0 = cHH * vHH[t].x, tHH1 = cHH * vHH[t].y;
            float4 o0, o1;
            o0.x = r0[t].x + (tLL0 + tLH0 + tHL0 + tHH0);
            o0.y = r0[t].y + (tLL0 + tLH0 - tHL0 - tHH0);
            o0.z = r0[t].z + (tLL1 + tLH1 + tHL1 + tHH1);
            o0.w = r0[t].w + (tLL1 + tLH1 - tHL1 - tHH1);
            o1.x = r1[t].x + (tLL0 - tLH0 + tHL0 - tHH0);
            o1.y = r1[t].y + (tLL0 - tLH0 - tHL0 + tHH0);
            o1.z = r1[t].z + (tLL1 - tLH1 + tHL1 - tHH1);
            o1.w = r1[t].w + (tLL1 - tLH1 - tHL1 + tHH1);
            *(float4*)(out + ioff[t]) = o0;
            *(float4*)(out + ioff[t] + 1024) = o1;
            mn = fminf(mn, fminf(fminf(fminf(o0.x, o0.y), fminf(o0.z, o0.w)),
                                 fminf(fminf(o1.x, o1.y), fminf(o1.z, o1.w))));
            mx = fmaxf(mx, fmaxf(fmaxf(fmaxf(o0.x, o0.y), fmaxf(o0.z, o0.w)),
                                 fmaxf(fmaxf(o1.x, o1.y), fmaxf(o1.z, o1.w))));
        }
    }

    unsigned kmn = f2key(mn), kmx = f2key(mx);
    for (int off = 32; off > 0; off >>= 1) {
        kmn = min(kmn, __shfl_down(kmn, off, 64));
        kmx = max(kmx, __shfl_down(kmx, off, 64));
    }
    __shared__ unsigned smn[4], smx[4];
    int lane = threadIdx.x & 63, wv = threadIdx.x >> 6;
    if (lane == 0) { smn[wv] = kmn; smx[wv] = kmx; }
    __syncthreads();
    if (threadIdx.x == 0) {
        unsigned rmn = min(min(smn[0], smn[1]), min(smn[2], smn[3]));
        unsigned rmx = max(max(smx[0], smx[1]), max(smx[2], smx[3]));
        atomicMin(&u[24 + b], rmn);
        atomicMax(&u[8 + b], rmx);
    }
}

// ---------------- K4: in-place normalize ----------------
// grid (128, 16) x 256; blockIdx.y = batch. Per batch 786432 float4, 24/thread,
// unroll x4. Final store is non-temporal (never re-read).
__global__ void k_norm(float* __restrict__ out, const unsigned* __restrict__ u) {
    const int b = blockIdx.y;
    const int S = gridDim.x * blockDim.x;       // 32768
    const int tid = blockIdx.x * blockDim.x + threadIdx.x;
    const int N4B = 3 * 1024 * 1024 / 4;        // 786432 float4 per batch

    float mnf = key2f(u[24 + b]);
    float inv = 1.0f / fmaxf(key2f(u[8 + b]) - mnf, EPSF);

    f32x4* o4 = (f32x4*)(out + (size_t)b * 3 * 1024 * 1024);
    for (int i = tid; i + 3 * S < N4B; i += 4 * S) {
        f32x4 v0 = o4[i], v1 = o4[i + S], v2 = o4[i + 2 * S], v3 = o4[i + 3 * S];
        v0 = (v0 - mnf) * inv;
        v1 = (v1 - mnf) * inv;
        v2 = (v2 - mnf) * inv;
        v3 = (v3 - mnf) * inv;
        __builtin_nontemporal_store(v0, &o4[i]);
        __builtin_nontemporal_store(v1, &o4[i + S]);
        __builtin_nontemporal_store(v2, &o4[i + 2 * S]);
        __builtin_nontemporal_store(v3, &o4[i + 3 * S]);
    }
}

extern "C" void kernel_launch(void* const* d_in, const int* in_sizes, int n_in,
                              void* d_out, int out_size, void* d_ws, size_t ws_size,
                              hipStream_t stream) {
    const float* img = (const float*)d_in[0];
    const float* nLL = (const float*)d_in[1];
    const float* nLH = (const float*)d_in[2];
    const float* nHL = (const float*)d_in[3];
    const float* nHH = (const float*)d_in[4];
    unsigned* u = (unsigned*)d_ws;
    float* out = (float*)d_out;

    // init reduction slots (ws is poisoned 0xAA before every call)
    hipMemsetAsync(d_ws, 0x00, 96, stream);              // u[0..23]
    hipMemsetAsync((char*)d_ws + 96, 0xFF, 64, stream);  // u[24..39]

    const int n4_noise = (16 * 3 * 512 * 512) / 4;       // 3,145,728 float4 per tensor
    k_maxabs<<<dim3(512, 4), 256, 0, stream>>>(nLL, nLH, nHL, nHH, u, n4_noise);

    k_enc_minmax<<<dim3(256, 16), 256, 0, stream>>>(img, nLL, nLH, nHL, nHH, u, out);

    k_norm<<<dim3(128, 16), 256, 0, stream>>>(out, u);
}